// Round 6
// baseline (165.108 us; speedup 1.0000x reference)
//
#include <hip/hip_runtime.h>
#include <hip/hip_bf16.h>

#define NMAX 20
#define NPAIR (NMAX * (NMAX - 1) / 2)   // 190
#define TPB 256
#define TOPK_BLOCKS 16
#define TOTAL_BLOCKS 2048               // = 256 CU x 8 blocks/CU, exact capacity
#define L1_BLOCKS (TOTAL_BLOCKS - TOPK_BLOCKS)  // 2032
#define UNROLL 8

// Native clang vector type: __builtin_nontemporal_load accepts these
// (HIP_vector_type float4 is a struct and is rejected).
typedef float f4 __attribute__((ext_vector_type(4)));

// Monotone map f32 -> u32 (order-preserving), packed with ~index so that
// u64 max == (max value, tie -> lowest index). Matches jax top_k tie rule.
__device__ __forceinline__ unsigned long long packKey(float v, unsigned i) {
    unsigned u = __float_as_uint(v);
    u = (u & 0x80000000u) ? ~u : (u | 0x80000000u);
    return ((unsigned long long)u << 32) | (unsigned long long)(~i);
}

__device__ __forceinline__ float absdiff4(f4 a, f4 b) {
    return fabsf(a.x - b.x) + fabsf(a.y - b.y) +
           fabsf(a.z - b.z) + fabsf(a.w - b.w);
}

// Single fused kernel:
//   blocks [0,16): block-top-20 of latent   -> keys
//   blocks [16,2048): L1 partial sums       -> partials
//   LAST block to finish (atomic counter) runs the finalize inline.
__global__ void __launch_bounds__(TPB, 4)
fused_all(const f4* __restrict__ t, const f4* __restrict__ p, int nvec,
          const float* __restrict__ latent, int nLat,
          const float* __restrict__ R_xyz, int G,
          float* __restrict__ partial, unsigned long long* __restrict__ keysOut,
          unsigned int* __restrict__ counter, float* __restrict__ out, float invN) {
    __shared__ float red[TPB];
    __shared__ unsigned long long ck[TOPK_BLOCKS * NMAX];   // 320 keys
    __shared__ unsigned long long wmax[TPB / 64];
    __shared__ unsigned long long selk;
    __shared__ int   sel[NMAX];
    __shared__ float sxyz[NMAX][3];
    __shared__ float s_l1, s_sum;
    __shared__ int   s_last;

    int tid = threadIdx.x, lane = tid & 63, wid = tid >> 6;

    if (blockIdx.x >= TOPK_BLOCKS) {
        // ---------------- L1 partial sums of |t - p| (non-temporal reads) ----
        int bid = blockIdx.x - TOPK_BLOCKS;
        int stride = L1_BLOCKS * TPB;
        int i = bid * TPB + tid;

        float acc[UNROLL];
        #pragma unroll
        for (int k = 0; k < UNROLL; ++k) acc[k] = 0.f;

        while (i + (UNROLL - 1) * stride < nvec) {
            f4 a[UNROLL], b[UNROLL];
            #pragma unroll
            for (int k = 0; k < UNROLL; ++k) a[k] = __builtin_nontemporal_load(&t[i + k * stride]);
            #pragma unroll
            for (int k = 0; k < UNROLL; ++k) b[k] = __builtin_nontemporal_load(&p[i + k * stride]);
            #pragma unroll
            for (int k = 0; k < UNROLL; ++k) acc[k] += absdiff4(a[k], b[k]);
            i += UNROLL * stride;
        }
        for (; i < nvec; i += stride)
            acc[0] += absdiff4(__builtin_nontemporal_load(&t[i]),
                               __builtin_nontemporal_load(&p[i]));

        float s = 0.f;
        #pragma unroll
        for (int k = 0; k < UNROLL; ++k) s += acc[k];

        #pragma unroll
        for (int o = 32; o > 0; o >>= 1) s += __shfl_down(s, o, 64);
        if (lane == 0) red[wid] = s;
        __syncthreads();
        if (tid == 0) {
            float tot = 0.f;
            #pragma unroll
            for (int w = 0; w < TPB / 64; ++w) tot += red[w];
            partial[bid] = tot;
        }
    } else {
        // ---------------- top-k partial: block-top-20 of a strided subset ----
        int b = blockIdx.x;          // 0..15

        unsigned long long loc[NMAX];
        #pragma unroll
        for (int k = 0; k < NMAX; ++k) loc[k] = 0ull;

        for (int i = b * TPB + tid; i < nLat; i += TOPK_BLOCKS * TPB) {
            unsigned long long key = packKey(latent[i], (unsigned)i);
            // Branch-free sorted insert, STATIC indices only (stays in VGPRs).
            #pragma unroll
            for (int k = NMAX - 1; k >= 1; --k) {
                loc[k] = (key > loc[k - 1]) ? loc[k - 1]
                                            : ((key > loc[k]) ? key : loc[k]);
            }
            loc[0] = (key > loc[0]) ? key : loc[0];
        }

        unsigned long long prev = ~0ull;
        for (int r = 0; r < NMAX; ++r) {
            unsigned long long m = 0ull;
            #pragma unroll
            for (int k = 0; k < NMAX; ++k) {
                unsigned long long c = loc[k];
                m = (c < prev && c > m) ? c : m;
            }
            #pragma unroll
            for (int o = 32; o > 0; o >>= 1) {
                unsigned long long other = __shfl_down(m, o, 64);
                if (other > m) m = other;
            }
            if (lane == 0) wmax[wid] = m;
            __syncthreads();
            if (tid == 0) {
                unsigned long long mm = wmax[0];
                #pragma unroll
                for (int w = 1; w < TPB / 64; ++w) if (wmax[w] > mm) mm = wmax[w];
                selk = mm;
                keysOut[b * NMAX + r] = mm;
            }
            __syncthreads();
            prev = selk;
        }
    }

    // ---------------- completion: last block runs the finalize ----------------
    __syncthreads();
    if (tid == 0) {
        __threadfence();                       // release our partial/keys
        unsigned int prevc = atomicAdd(counter, 1u);
        s_last = (prevc == TOTAL_BLOCKS - 1) ? 1 : 0;
    }
    __syncthreads();
    if (!s_last) return;
    __threadfence();                           // acquire everyone's writes

    // ---- Phase 1: reduce L1 partials (deterministic order) ----
    {
        float s = 0.f;
        for (int i = tid; i < L1_BLOCKS; i += TPB) s += partial[i];
        red[tid] = s;
        __syncthreads();
        for (int off = TPB / 2; off > 0; off >>= 1) {
            if (tid < off) red[tid] += red[tid + off];
            __syncthreads();
        }
        if (tid == 0) s_l1 = red[0] * invN;
        __syncthreads();
    }

    // ---- Phase 2: merge the 16 block-top-20 lists -> global top-20 ----
    for (int i = tid; i < TOPK_BLOCKS * NMAX; i += TPB) ck[i] = keysOut[i];
    __syncthreads();
    {
        unsigned long long prev = ~0ull;
        for (int r = 0; r < NMAX; ++r) {
            unsigned long long m = 0ull;
            for (int i = tid; i < TOPK_BLOCKS * NMAX; i += TPB) {
                unsigned long long c = ck[i];
                m = (c < prev && c > m) ? c : m;
            }
            #pragma unroll
            for (int o = 32; o > 0; o >>= 1) {
                unsigned long long other = __shfl_down(m, o, 64);
                if (other > m) m = other;
            }
            if (lane == 0) wmax[wid] = m;
            __syncthreads();
            if (tid == 0) {
                unsigned long long mm = wmax[0];
                #pragma unroll
                for (int w = 1; w < TPB / 64; ++w) if (wmax[w] > mm) mm = wmax[w];
                selk = mm;
                sel[r] = (int)(~(unsigned)mm);
            }
            __syncthreads();
            prev = selk;
        }
    }

    // ---- Phase 3: gather xyz of selected points ----
    if (tid < NMAX * 3) {
        int i = tid / 3, d = tid % 3;
        sxyz[i][d] = R_xyz[d * G + sel[i]];
    }
    __syncthreads();

    // ---- Phase 4: 190 pairwise distances, std (ddof=1) ----
    float dval = 0.f;
    if (tid < NPAIR) {
        int k = tid, i = 0, rem = NMAX - 1;
        while (k >= rem) { k -= rem; ++i; --rem; }
        int j = i + 1 + k;
        float dx = sxyz[i][0] - sxyz[j][0];
        float dy = sxyz[i][1] - sxyz[j][1];
        float dz = sxyz[i][2] - sxyz[j][2];
        dval = sqrtf(dx * dx + dy * dy + dz * dz);
    }
    red[tid] = dval;
    __syncthreads();
    for (int off = TPB / 2; off > 0; off >>= 1) {
        if (tid < off) red[tid] += red[tid + off];
        __syncthreads();
    }
    if (tid == 0) s_sum = red[0];
    __syncthreads();
    red[tid] = dval * dval;
    __syncthreads();
    for (int off = TPB / 2; off > 0; off >>= 1) {
        if (tid < off) red[tid] += red[tid + off];
        __syncthreads();
    }
    if (tid == 0) {
        float sum   = s_sum;
        float sumsq = red[0];
        float mean  = sum / (float)NPAIR;
        float var   = (sumsq - (float)NPAIR * mean * mean) / (float)(NPAIR - 1);
        float stdv  = sqrtf(fmaxf(var, 0.f));
        float reg   = 0.01f * stdv;
        out[0] = s_l1 + reg;
        out[1] = s_l1;
        out[2] = reg;
    }
}

extern "C" void kernel_launch(void* const* d_in, const int* in_sizes, int n_in,
                              void* d_out, int out_size, void* d_ws, size_t ws_size,
                              hipStream_t stream) {
    const float* target = (const float*)d_in[0];
    const float* pred   = (const float*)d_in[1];
    const float* latent = (const float*)d_in[2];
    const float* R_xyz  = (const float*)d_in[3];
    float* out = (float*)d_out;

    int n    = in_sizes[0];          // 33,554,432
    int nLat = in_sizes[2];          // 64,800
    int G    = in_sizes[3] / 3;      // 64,800
    int nvec = n / 4;

    // ws layout: counter @0 (4B), partials @64 (2032 floats), keys @8256 (320 u64).
    unsigned int* counter = (unsigned int*)d_ws;
    float* partials = (float*)((char*)d_ws + 64);
    unsigned long long* keys = (unsigned long long*)((char*)d_ws + 64 + 8192);

    (void)hipMemsetAsync(counter, 0, sizeof(unsigned int), stream);

    fused_all<<<TOTAL_BLOCKS, TPB, 0, stream>>>(
        (const f4*)target, (const f4*)pred, nvec,
        latent, nLat, R_xyz, G, partials, keys, counter, out, 1.0f / (float)n);
}

// Round 7
// 135.703 us; speedup vs baseline: 1.2167x; 1.2167x over previous
//
#include <hip/hip_runtime.h>
#include <hip/hip_bf16.h>

#define NMAX 20
#define NPAIR (NMAX * (NMAX - 1) / 2)   // 190
#define TPB 256
#define TOPK_BLOCKS 16
#define TOTAL_BLOCKS 2048               // = 256 CU x 8 blocks/CU
#define UNROLL 8

typedef float f4 __attribute__((ext_vector_type(4)));

// Monotone map f32 -> u32 (order-preserving), packed with ~index so that
// u64 max == (max value, tie -> lowest index). Matches jax top_k tie rule.
__device__ __forceinline__ unsigned long long packKey(float v, unsigned i) {
    unsigned u = __float_as_uint(v);
    u = (u & 0x80000000u) ? ~u : (u | 0x80000000u);
    return ((unsigned long long)u << 32) | (unsigned long long)(~i);
}

__device__ __forceinline__ float absdiff4(f4 a, f4 b) {
    return fabsf(a.x - b.x) + fabsf(a.y - b.y) +
           fabsf(a.z - b.z) + fabsf(a.w - b.w);
}

// Single fused kernel:
//   ALL blocks: L1 partial over a CONTIGUOUS chunk of the arrays
//   blocks [0,16): additionally block-top-20 of latent -> keys
//   LAST block to finish (atomic counter) runs the finalize inline.
__global__ void __launch_bounds__(TPB, 4)
fused_all(const f4* __restrict__ t, const f4* __restrict__ p, int nvec, int chunk,
          const float* __restrict__ latent, int nLat,
          const float* __restrict__ R_xyz, int G,
          float* __restrict__ partial, unsigned long long* __restrict__ keysOut,
          unsigned int* __restrict__ counter, float* __restrict__ out, float invN) {
    __shared__ float red[TPB];
    __shared__ unsigned long long ck[TOPK_BLOCKS * NMAX];   // 320 keys
    __shared__ unsigned long long wmax[TPB / 64];
    __shared__ unsigned long long selk;
    __shared__ int   sel[NMAX];
    __shared__ float sxyz[NMAX][3];
    __shared__ float s_l1, s_sum;
    __shared__ int   s_last;

    int tid = threadIdx.x, lane = tid & 63, wid = tid >> 6;

    // ---------------- L1 partial: contiguous chunk [start, end) ----------------
    {
        int start = blockIdx.x * chunk;
        int end   = start + chunk;
        if (end > nvec) end = nvec;

        float acc[UNROLL];
        #pragma unroll
        for (int k = 0; k < UNROLL; ++k) acc[k] = 0.f;

        int i = start + tid;
        // Main: UNROLL iterations spaced TPB apart (32KB window), all loads
        // issued before consumption; static indices -> VGPRs.
        while (i + (UNROLL - 1) * TPB < end) {
            f4 a[UNROLL], b[UNROLL];
            #pragma unroll
            for (int k = 0; k < UNROLL; ++k) a[k] = t[i + k * TPB];
            #pragma unroll
            for (int k = 0; k < UNROLL; ++k) b[k] = p[i + k * TPB];
            #pragma unroll
            for (int k = 0; k < UNROLL; ++k) acc[k] += absdiff4(a[k], b[k]);
            i += UNROLL * TPB;
        }
        for (; i < end; i += TPB) acc[0] += absdiff4(t[i], p[i]);

        float s = 0.f;
        #pragma unroll
        for (int k = 0; k < UNROLL; ++k) s += acc[k];

        #pragma unroll
        for (int o = 32; o > 0; o >>= 1) s += __shfl_down(s, o, 64);
        if (lane == 0) red[wid] = s;
        __syncthreads();
        if (tid == 0) {
            float tot = 0.f;
            #pragma unroll
            for (int w = 0; w < TPB / 64; ++w) tot += red[w];
            partial[blockIdx.x] = tot;
        }
        __syncthreads();
    }

    // ---------------- blocks [0,16): block-top-20 of a strided subset ----------
    if (blockIdx.x < TOPK_BLOCKS) {
        int b = blockIdx.x;

        unsigned long long loc[NMAX];
        #pragma unroll
        for (int k = 0; k < NMAX; ++k) loc[k] = 0ull;

        for (int i = b * TPB + tid; i < nLat; i += TOPK_BLOCKS * TPB) {
            unsigned long long key = packKey(latent[i], (unsigned)i);
            // Branch-free sorted insert, STATIC indices only (stays in VGPRs).
            #pragma unroll
            for (int k = NMAX - 1; k >= 1; --k) {
                loc[k] = (key > loc[k - 1]) ? loc[k - 1]
                                            : ((key > loc[k]) ? key : loc[k]);
            }
            loc[0] = (key > loc[0]) ? key : loc[0];
        }

        unsigned long long prev = ~0ull;
        for (int r = 0; r < NMAX; ++r) {
            unsigned long long m = 0ull;
            #pragma unroll
            for (int k = 0; k < NMAX; ++k) {
                unsigned long long c = loc[k];
                m = (c < prev && c > m) ? c : m;
            }
            #pragma unroll
            for (int o = 32; o > 0; o >>= 1) {
                unsigned long long other = __shfl_down(m, o, 64);
                if (other > m) m = other;
            }
            if (lane == 0) wmax[wid] = m;
            __syncthreads();
            if (tid == 0) {
                unsigned long long mm = wmax[0];
                #pragma unroll
                for (int w = 1; w < TPB / 64; ++w) if (wmax[w] > mm) mm = wmax[w];
                selk = mm;
                keysOut[b * NMAX + r] = mm;
            }
            __syncthreads();
            prev = selk;
        }
    }

    // ---------------- completion: last block runs the finalize ----------------
    __syncthreads();
    if (tid == 0) {
        __threadfence();                       // release our partial/keys
        unsigned int prevc = atomicAdd(counter, 1u);
        s_last = (prevc == TOTAL_BLOCKS - 1) ? 1 : 0;
    }
    __syncthreads();
    if (!s_last) return;
    __threadfence();                           // acquire everyone's writes

    // ---- Phase 1: reduce L1 partials (deterministic order) ----
    {
        float s = 0.f;
        for (int i = tid; i < TOTAL_BLOCKS; i += TPB) s += partial[i];
        red[tid] = s;
        __syncthreads();
        for (int off = TPB / 2; off > 0; off >>= 1) {
            if (tid < off) red[tid] += red[tid + off];
            __syncthreads();
        }
        if (tid == 0) s_l1 = red[0] * invN;
        __syncthreads();
    }

    // ---- Phase 2: merge the 16 block-top-20 lists -> global top-20 ----
    for (int i = tid; i < TOPK_BLOCKS * NMAX; i += TPB) ck[i] = keysOut[i];
    __syncthreads();
    {
        unsigned long long prev = ~0ull;
        for (int r = 0; r < NMAX; ++r) {
            unsigned long long m = 0ull;
            for (int i = tid; i < TOPK_BLOCKS * NMAX; i += TPB) {
                unsigned long long c = ck[i];
                m = (c < prev && c > m) ? c : m;
            }
            #pragma unroll
            for (int o = 32; o > 0; o >>= 1) {
                unsigned long long other = __shfl_down(m, o, 64);
                if (other > m) m = other;
            }
            if (lane == 0) wmax[wid] = m;
            __syncthreads();
            if (tid == 0) {
                unsigned long long mm = wmax[0];
                #pragma unroll
                for (int w = 1; w < TPB / 64; ++w) if (wmax[w] > mm) mm = wmax[w];
                selk = mm;
                sel[r] = (int)(~(unsigned)mm);
            }
            __syncthreads();
            prev = selk;
        }
    }

    // ---- Phase 3: gather xyz of selected points ----
    if (tid < NMAX * 3) {
        int i = tid / 3, d = tid % 3;
        sxyz[i][d] = R_xyz[d * G + sel[i]];
    }
    __syncthreads();

    // ---- Phase 4: 190 pairwise distances, std (ddof=1) ----
    float dval = 0.f;
    if (tid < NPAIR) {
        int k = tid, i = 0, rem = NMAX - 1;
        while (k >= rem) { k -= rem; ++i; --rem; }
        int j = i + 1 + k;
        float dx = sxyz[i][0] - sxyz[j][0];
        float dy = sxyz[i][1] - sxyz[j][1];
        float dz = sxyz[i][2] - sxyz[j][2];
        dval = sqrtf(dx * dx + dy * dy + dz * dz);
    }
    red[tid] = dval;
    __syncthreads();
    for (int off = TPB / 2; off > 0; off >>= 1) {
        if (tid < off) red[tid] += red[tid + off];
        __syncthreads();
    }
    if (tid == 0) s_sum = red[0];
    __syncthreads();
    red[tid] = dval * dval;
    __syncthreads();
    for (int off = TPB / 2; off > 0; off >>= 1) {
        if (tid < off) red[tid] += red[tid + off];
        __syncthreads();
    }
    if (tid == 0) {
        float sum   = s_sum;
        float sumsq = red[0];
        float mean  = sum / (float)NPAIR;
        float var   = (sumsq - (float)NPAIR * mean * mean) / (float)(NPAIR - 1);
        float stdv  = sqrtf(fmaxf(var, 0.f));
        float reg   = 0.01f * stdv;
        out[0] = s_l1 + reg;
        out[1] = s_l1;
        out[2] = reg;
    }
}

extern "C" void kernel_launch(void* const* d_in, const int* in_sizes, int n_in,
                              void* d_out, int out_size, void* d_ws, size_t ws_size,
                              hipStream_t stream) {
    const float* target = (const float*)d_in[0];
    const float* pred   = (const float*)d_in[1];
    const float* latent = (const float*)d_in[2];
    const float* R_xyz  = (const float*)d_in[3];
    float* out = (float*)d_out;

    int n    = in_sizes[0];          // 33,554,432
    int nLat = in_sizes[2];          // 64,800
    int G    = in_sizes[3] / 3;      // 64,800
    int nvec = n / 4;                // 8,388,608 float4
    int chunk = (nvec + TOTAL_BLOCKS - 1) / TOTAL_BLOCKS;   // 4096 exactly

    // ws layout: counter @0 (4B), partials @64 (2048 floats), keys after.
    unsigned int* counter = (unsigned int*)d_ws;
    float* partials = (float*)((char*)d_ws + 64);
    unsigned long long* keys = (unsigned long long*)((char*)d_ws + 64 + TOTAL_BLOCKS * sizeof(float));

    (void)hipMemsetAsync(counter, 0, sizeof(unsigned int), stream);

    fused_all<<<TOTAL_BLOCKS, TPB, 0, stream>>>(
        (const f4*)target, (const f4*)pred, nvec, chunk,
        latent, nLat, R_xyz, G, partials, keys, counter, out, 1.0f / (float)n);
}

// Round 8
// 84.156 us; speedup vs baseline: 1.9619x; 1.6125x over previous
//
#include <hip/hip_runtime.h>
#include <hip/hip_bf16.h>

#define NMAX 20
#define NPAIR (NMAX * (NMAX - 1) / 2)   // 190
#define TPB 256
#define TOPK_BLOCKS 16
#define L1_BLOCKS 1024
#define CHUNK 512                        // float4 per array per round per block (8KB)

typedef float f4 __attribute__((ext_vector_type(4)));

// global -> LDS direct DMA, 16B per lane. LDS dest is wave-uniform base
// (HW adds lane*16); global src is per-lane.
#define GLD16(gp, lp) __builtin_amdgcn_global_load_lds(                        \
    (__attribute__((address_space(1))) void*)(gp),                             \
    (__attribute__((address_space(3))) void*)(lp), 16, 0, 0)

// Monotone map f32 -> u32 (order-preserving), packed with ~index so that
// u64 max == (max value, tie -> lowest index). Matches jax top_k tie rule.
__device__ __forceinline__ unsigned long long packKey(float v, unsigned i) {
    unsigned u = __float_as_uint(v);
    u = (u & 0x80000000u) ? ~u : (u | 0x80000000u);
    return ((unsigned long long)u << 32) | (unsigned long long)(~i);
}

__device__ __forceinline__ float absdiff4(f4 a, f4 b) {
    return fabsf(a.x - b.x) + fabsf(a.y - b.y) +
           fabsf(a.z - b.z) + fabsf(a.w - b.w);
}

// Kernel 1: L1 partial sums via global_load_lds double-buffered staging.
// Blocks 0..15 additionally compute block-top-20 of latent after their L1 work.
__global__ void __launch_bounds__(TPB, 4)
l1_topk_kernel(const f4* __restrict__ t, const f4* __restrict__ p, int nvec,
               const float* __restrict__ latent, int nLat,
               float* __restrict__ partial, unsigned long long* __restrict__ keysOut,
               int rounds) {
    __shared__ f4 lA[2][CHUNK];          // 16 KB
    __shared__ f4 lB[2][CHUNK];          // 16 KB
    __shared__ float red[TPB / 64];
    __shared__ unsigned long long wmax[TPB / 64];
    __shared__ unsigned long long selk;

    int tid = threadIdx.x, lane = tid & 63, w = tid >> 6;
    int b = blockIdx.x;

    float acc = 0.f;

    // prologue: stage round 0 into buffer 0 (block-cyclic chunk c = r*L1_BLOCKS + b)
    {
        long base = (long)b * CHUNK + w * 128 + lane;
        GLD16(t + base,      &lA[0][w * 128]);
        GLD16(t + base + 64, &lA[0][w * 128 + 64]);
        GLD16(p + base,      &lB[0][w * 128]);
        GLD16(p + base + 64, &lB[0][w * 128 + 64]);
    }

    for (int r = 0; r < rounds; ++r) {
        int d = r & 1;
        __syncthreads();                 // vmcnt(0)+lgkmcnt(0) drain + barrier:
                                         // round r fully staged, prev reads done
        acc += absdiff4(lA[d][tid],       lB[d][tid]);
        acc += absdiff4(lA[d][tid + 256], lB[d][tid + 256]);

        if (r + 1 < rounds) {            // issue next round into other buffer
            long c = (long)(r + 1) * L1_BLOCKS + b;
            long base = c * CHUNK + w * 128 + lane;
            GLD16(t + base,      &lA[d ^ 1][w * 128]);
            GLD16(t + base + 64, &lA[d ^ 1][w * 128 + 64]);
            GLD16(p + base,      &lB[d ^ 1][w * 128]);
            GLD16(p + base + 64, &lB[d ^ 1][w * 128 + 64]);
        }
    }

    // generic remainder (empty for the 32x512x2048 shape)
    {
        long done = (long)rounds * L1_BLOCKS * CHUNK;
        for (long i = done + (long)b * TPB + tid; i < nvec; i += (long)L1_BLOCKS * TPB)
            acc += absdiff4(t[i], p[i]);
    }

    // block reduce -> partial[b]
    #pragma unroll
    for (int o = 32; o > 0; o >>= 1) acc += __shfl_down(acc, o, 64);
    if (lane == 0) red[w] = acc;
    __syncthreads();
    if (tid == 0) {
        float tot = 0.f;
        #pragma unroll
        for (int k = 0; k < TPB / 64; ++k) tot += red[k];
        partial[b] = tot;
    }

    // ---------------- blocks [0,16): block-top-20 of a strided subset ----------
    if (b < TOPK_BLOCKS) {
        unsigned long long loc[NMAX];
        #pragma unroll
        for (int k = 0; k < NMAX; ++k) loc[k] = 0ull;

        for (int i = b * TPB + tid; i < nLat; i += TOPK_BLOCKS * TPB) {
            unsigned long long key = packKey(latent[i], (unsigned)i);
            // Branch-free sorted insert, STATIC indices only (stays in VGPRs).
            #pragma unroll
            for (int k = NMAX - 1; k >= 1; --k) {
                loc[k] = (key > loc[k - 1]) ? loc[k - 1]
                                            : ((key > loc[k]) ? key : loc[k]);
            }
            loc[0] = (key > loc[0]) ? key : loc[0];
        }

        unsigned long long prev = ~0ull;
        for (int r = 0; r < NMAX; ++r) {
            unsigned long long m = 0ull;
            #pragma unroll
            for (int k = 0; k < NMAX; ++k) {
                unsigned long long c = loc[k];
                m = (c < prev && c > m) ? c : m;
            }
            #pragma unroll
            for (int o = 32; o > 0; o >>= 1) {
                unsigned long long other = __shfl_down(m, o, 64);
                if (other > m) m = other;
            }
            if (lane == 0) wmax[w] = m;
            __syncthreads();
            if (tid == 0) {
                unsigned long long mm = wmax[0];
                #pragma unroll
                for (int k = 1; k < TPB / 64; ++k) if (wmax[k] > mm) mm = wmax[k];
                selk = mm;
                keysOut[b * NMAX + r] = mm;
            }
            __syncthreads();
            prev = selk;
        }
    }
}

// ---------------- Kernel 2: finalize (merge + pdist std + combine) ------------
__global__ void __launch_bounds__(TPB)
finalize_kernel(const float* __restrict__ partials, int nPartials,
                const unsigned long long* __restrict__ keys,  // TOPK_BLOCKS*NMAX
                const float* __restrict__ R_xyz, int G,
                float* __restrict__ out, float invN) {
    __shared__ float red[TPB];
    __shared__ unsigned long long ck[TOPK_BLOCKS * NMAX];   // 320 keys
    __shared__ unsigned long long wmax[TPB / 64];
    __shared__ unsigned long long selk;
    __shared__ int   sel[NMAX];
    __shared__ float sxyz[NMAX][3];
    __shared__ float s_l1, s_sum;

    int tid = threadIdx.x, lane = tid & 63, wid = tid >> 6;

    // ---- Phase 1: reduce L1 partials (deterministic order) ----
    {
        float s = 0.f;
        for (int i = tid; i < nPartials; i += TPB) s += partials[i];
        red[tid] = s;
        __syncthreads();
        for (int off = TPB / 2; off > 0; off >>= 1) {
            if (tid < off) red[tid] += red[tid + off];
            __syncthreads();
        }
        if (tid == 0) s_l1 = red[0] * invN;
        __syncthreads();
    }

    // ---- Phase 2: merge the 16 block-top-20 lists -> global top-20 ----
    for (int i = tid; i < TOPK_BLOCKS * NMAX; i += TPB) ck[i] = keys[i];
    __syncthreads();
    {
        unsigned long long prev = ~0ull;
        for (int r = 0; r < NMAX; ++r) {
            unsigned long long m = 0ull;
            for (int i = tid; i < TOPK_BLOCKS * NMAX; i += TPB) {
                unsigned long long c = ck[i];
                m = (c < prev && c > m) ? c : m;
            }
            #pragma unroll
            for (int o = 32; o > 0; o >>= 1) {
                unsigned long long other = __shfl_down(m, o, 64);
                if (other > m) m = other;
            }
            if (lane == 0) wmax[wid] = m;
            __syncthreads();
            if (tid == 0) {
                unsigned long long mm = wmax[0];
                #pragma unroll
                for (int w = 1; w < TPB / 64; ++w) if (wmax[w] > mm) mm = wmax[w];
                selk = mm;
                sel[r] = (int)(~(unsigned)mm);
            }
            __syncthreads();
            prev = selk;
        }
    }

    // ---- Phase 3: gather xyz of selected points ----
    if (tid < NMAX * 3) {
        int i = tid / 3, d = tid % 3;
        sxyz[i][d] = R_xyz[d * G + sel[i]];
    }
    __syncthreads();

    // ---- Phase 4: 190 pairwise distances, std (ddof=1) ----
    float dval = 0.f;
    if (tid < NPAIR) {
        int k = tid, i = 0, rem = NMAX - 1;
        while (k >= rem) { k -= rem; ++i; --rem; }
        int j = i + 1 + k;
        float dx = sxyz[i][0] - sxyz[j][0];
        float dy = sxyz[i][1] - sxyz[j][1];
        float dz = sxyz[i][2] - sxyz[j][2];
        dval = sqrtf(dx * dx + dy * dy + dz * dz);
    }
    red[tid] = dval;
    __syncthreads();
    for (int off = TPB / 2; off > 0; off >>= 1) {
        if (tid < off) red[tid] += red[tid + off];
        __syncthreads();
    }
    if (tid == 0) s_sum = red[0];
    __syncthreads();
    red[tid] = dval * dval;
    __syncthreads();
    for (int off = TPB / 2; off > 0; off >>= 1) {
        if (tid < off) red[tid] += red[tid + off];
        __syncthreads();
    }
    if (tid == 0) {
        float sum   = s_sum;
        float sumsq = red[0];
        float mean  = sum / (float)NPAIR;
        float var   = (sumsq - (float)NPAIR * mean * mean) / (float)(NPAIR - 1);
        float stdv  = sqrtf(fmaxf(var, 0.f));
        float reg   = 0.01f * stdv;
        out[0] = s_l1 + reg;
        out[1] = s_l1;
        out[2] = reg;
    }
}

extern "C" void kernel_launch(void* const* d_in, const int* in_sizes, int n_in,
                              void* d_out, int out_size, void* d_ws, size_t ws_size,
                              hipStream_t stream) {
    const float* target = (const float*)d_in[0];
    const float* pred   = (const float*)d_in[1];
    const float* latent = (const float*)d_in[2];
    const float* R_xyz  = (const float*)d_in[3];
    float* out = (float*)d_out;

    int n    = in_sizes[0];          // 33,554,432
    int nLat = in_sizes[2];          // 64,800
    int G    = in_sizes[3] / 3;      // 64,800
    int nvec = n / 4;                // 8,388,608 float4
    int rounds = nvec / (L1_BLOCKS * CHUNK);   // 16 for this shape

    // ws layout: partials @0 (1024 floats), keys @4096 (320 u64).
    float* partials = (float*)d_ws;
    unsigned long long* keys = (unsigned long long*)((char*)d_ws + L1_BLOCKS * sizeof(float));

    l1_topk_kernel<<<L1_BLOCKS, TPB, 0, stream>>>(
        (const f4*)target, (const f4*)pred, nvec,
        latent, nLat, partials, keys, rounds);

    finalize_kernel<<<1, TPB, 0, stream>>>(
        partials, L1_BLOCKS, keys, R_xyz, G, out, 1.0f / (float)n);
}

// Round 9
// 72.332 us; speedup vs baseline: 2.2826x; 1.1635x over previous
//
#include <hip/hip_runtime.h>
#include <hip/hip_bf16.h>

#define NMAX 20
#define NPAIR (NMAX * (NMAX - 1) / 2)   // 190
#define TPB 256
#define L1_BLOCKS 2048
#define TOPK_BLOCKS 16
#define UNROLL 8

// Monotone map f32 -> u32 (order-preserving), packed with ~index so that
// u64 max == (max value, tie -> lowest index). Matches jax top_k tie rule.
__device__ __forceinline__ unsigned long long packKey(float v, unsigned i) {
    unsigned u = __float_as_uint(v);
    u = (u & 0x80000000u) ? ~u : (u | 0x80000000u);
    return ((unsigned long long)u << 32) | (unsigned long long)(~i);
}

__device__ __forceinline__ float absdiff4(float4 a, float4 b) {
    return fabsf(a.x - b.x) + fabsf(a.y - b.y) +
           fabsf(a.z - b.z) + fabsf(a.w - b.w);
}

// ------------- Kernel 1 (fused): topk blocks [0,16) + L1 blocks [16, 16+2048) -
// launch_bounds(256, 4): relaxed VGPR budget for the batched loads.
__global__ void __launch_bounds__(TPB, 4)
fused_kernel(const float4* __restrict__ t, const float4* __restrict__ p, int nvec,
             const float* __restrict__ latent, int nLat,
             float* __restrict__ partial, unsigned long long* __restrict__ keysOut) {
    if (blockIdx.x >= TOPK_BLOCKS) {
        // ---------------- L1 partial sums of |t - p| ----------------
        int bid = blockIdx.x - TOPK_BLOCKS;
        int stride = L1_BLOCKS * TPB;
        int i = bid * TPB + threadIdx.x;

        float acc[UNROLL];
        #pragma unroll
        for (int k = 0; k < UNROLL; ++k) acc[k] = 0.f;

        // Main: issue ALL 2*UNROLL independent 16B loads, then consume.
        // Static indices only -> arrays live in VGPRs (no scratch).
        while (i + (UNROLL - 1) * stride < nvec) {
            float4 a[UNROLL], b[UNROLL];
            #pragma unroll
            for (int k = 0; k < UNROLL; ++k) a[k] = t[i + k * stride];
            #pragma unroll
            for (int k = 0; k < UNROLL; ++k) b[k] = p[i + k * stride];
            #pragma unroll
            for (int k = 0; k < UNROLL; ++k) acc[k] += absdiff4(a[k], b[k]);
            i += UNROLL * stride;
        }
        // Tail (not taken for the 32x512x2048 shape: nvec == 16*stride)
        for (; i < nvec; i += stride) acc[0] += absdiff4(t[i], p[i]);

        float s = 0.f;
        #pragma unroll
        for (int k = 0; k < UNROLL; ++k) s += acc[k];

        #pragma unroll
        for (int o = 32; o > 0; o >>= 1) s += __shfl_down(s, o, 64);
        __shared__ float wsum[TPB / 64];
        int lane = threadIdx.x & 63;
        int wid  = threadIdx.x >> 6;
        if (lane == 0) wsum[wid] = s;
        __syncthreads();
        if (threadIdx.x == 0) {
            float tot = 0.f;
            #pragma unroll
            for (int w = 0; w < TPB / 64; ++w) tot += wsum[w];
            partial[bid] = tot;
        }
    } else {
        // ---------------- top-k partial: block-top-20 of a strided subset ----
        int b   = blockIdx.x;          // 0..15
        int tid = threadIdx.x;
        int lane = tid & 63, wid = tid >> 6;

        // Per-thread top-20 in REGISTERS (sentinel 0 < any real key).
        unsigned long long loc[NMAX];
        #pragma unroll
        for (int k = 0; k < NMAX; ++k) loc[k] = 0ull;

        for (int i = b * TPB + tid; i < nLat; i += TOPK_BLOCKS * TPB) {
            unsigned long long key = packKey(latent[i], (unsigned)i);
            // Branch-free sorted insert, STATIC indices only (stays in VGPRs).
            #pragma unroll
            for (int k = NMAX - 1; k >= 1; --k) {
                loc[k] = (key > loc[k - 1]) ? loc[k - 1]
                                            : ((key > loc[k]) ? key : loc[k]);
            }
            loc[0] = (key > loc[0]) ? key : loc[0];
        }

        // Block-level: 20 rounds of argmax with "key < prev" exclusion.
        __shared__ unsigned long long wmax[TPB / 64];
        __shared__ unsigned long long selk;
        unsigned long long prev = ~0ull;
        for (int r = 0; r < NMAX; ++r) {
            unsigned long long m = 0ull;
            #pragma unroll
            for (int k = 0; k < NMAX; ++k) {
                unsigned long long c = loc[k];
                m = (c < prev && c > m) ? c : m;
            }
            #pragma unroll
            for (int o = 32; o > 0; o >>= 1) {
                unsigned long long other = __shfl_down(m, o, 64);
                if (other > m) m = other;
            }
            if (lane == 0) wmax[wid] = m;
            __syncthreads();
            if (tid == 0) {
                unsigned long long mm = wmax[0];
                #pragma unroll
                for (int w = 1; w < TPB / 64; ++w) if (wmax[w] > mm) mm = wmax[w];
                selk = mm;
                keysOut[b * NMAX + r] = mm;
            }
            __syncthreads();
            prev = selk;
        }
    }
}

// ---------------- Kernel 2: finalize (merge + pdist std + combine) ------------
__global__ void __launch_bounds__(TPB)
finalize_kernel(const float* __restrict__ partials, int nPartials,
                const unsigned long long* __restrict__ keys,  // TOPK_BLOCKS*NMAX
                const float* __restrict__ R_xyz, int G,
                float* __restrict__ out, float invN) {
    __shared__ float red[TPB];
    __shared__ unsigned long long ck[TOPK_BLOCKS * NMAX];   // 320 keys
    __shared__ unsigned long long wmax[TPB / 64];
    __shared__ unsigned long long selk;
    __shared__ int   sel[NMAX];
    __shared__ float sxyz[NMAX][3];
    __shared__ float s_l1, s_sum;

    int tid = threadIdx.x, lane = tid & 63, wid = tid >> 6;

    // ---- Phase 1: reduce L1 partials (deterministic order) ----
    {
        float s = 0.f;
        for (int i = tid; i < nPartials; i += TPB) s += partials[i];
        red[tid] = s;
        __syncthreads();
        for (int off = TPB / 2; off > 0; off >>= 1) {
            if (tid < off) red[tid] += red[tid + off];
            __syncthreads();
        }
        if (tid == 0) s_l1 = red[0] * invN;
        __syncthreads();
    }

    // ---- Phase 2: merge the 16 block-top-20 lists -> global top-20 ----
    for (int i = tid; i < TOPK_BLOCKS * NMAX; i += TPB) ck[i] = keys[i];
    __syncthreads();
    {
        unsigned long long prev = ~0ull;
        for (int r = 0; r < NMAX; ++r) {
            unsigned long long m = 0ull;
            for (int i = tid; i < TOPK_BLOCKS * NMAX; i += TPB) {
                unsigned long long c = ck[i];
                m = (c < prev && c > m) ? c : m;
            }
            #pragma unroll
            for (int o = 32; o > 0; o >>= 1) {
                unsigned long long other = __shfl_down(m, o, 64);
                if (other > m) m = other;
            }
            if (lane == 0) wmax[wid] = m;
            __syncthreads();
            if (tid == 0) {
                unsigned long long mm = wmax[0];
                #pragma unroll
                for (int w = 1; w < TPB / 64; ++w) if (wmax[w] > mm) mm = wmax[w];
                selk = mm;
                sel[r] = (int)(~(unsigned)mm);
            }
            __syncthreads();
            prev = selk;
        }
    }

    // ---- Phase 3: gather xyz of selected points ----
    if (tid < NMAX * 3) {
        int i = tid / 3, d = tid % 3;
        sxyz[i][d] = R_xyz[d * G + sel[i]];
    }
    __syncthreads();

    // ---- Phase 4: 190 pairwise distances, std (ddof=1) ----
    float dval = 0.f;
    if (tid < NPAIR) {
        int k = tid, i = 0, rem = NMAX - 1;
        while (k >= rem) { k -= rem; ++i; --rem; }
        int j = i + 1 + k;
        float dx = sxyz[i][0] - sxyz[j][0];
        float dy = sxyz[i][1] - sxyz[j][1];
        float dz = sxyz[i][2] - sxyz[j][2];
        dval = sqrtf(dx * dx + dy * dy + dz * dz);
    }
    red[tid] = dval;
    __syncthreads();
    for (int off = TPB / 2; off > 0; off >>= 1) {
        if (tid < off) red[tid] += red[tid + off];
        __syncthreads();
    }
    if (tid == 0) s_sum = red[0];
    __syncthreads();
    red[tid] = dval * dval;
    __syncthreads();
    for (int off = TPB / 2; off > 0; off >>= 1) {
        if (tid < off) red[tid] += red[tid + off];
        __syncthreads();
    }
    if (tid == 0) {
        float sum   = s_sum;
        float sumsq = red[0];
        float mean  = sum / (float)NPAIR;
        float var   = (sumsq - (float)NPAIR * mean * mean) / (float)(NPAIR - 1);
        float stdv  = sqrtf(fmaxf(var, 0.f));
        float reg   = 0.01f * stdv;
        out[0] = s_l1 + reg;
        out[1] = s_l1;
        out[2] = reg;
    }
}

extern "C" void kernel_launch(void* const* d_in, const int* in_sizes, int n_in,
                              void* d_out, int out_size, void* d_ws, size_t ws_size,
                              hipStream_t stream) {
    const float* target = (const float*)d_in[0];
    const float* pred   = (const float*)d_in[1];
    const float* latent = (const float*)d_in[2];
    const float* R_xyz  = (const float*)d_in[3];
    float* out = (float*)d_out;

    int n    = in_sizes[0];          // 33,554,432
    int nLat = in_sizes[2];          // 64,800
    int G    = in_sizes[3] / 3;      // 64,800
    int nvec = n / 4;

    // ws layout: [0, 2048) floats = L1 partials; then 16*20 u64 keys.
    float* partials = (float*)d_ws;
    unsigned long long* keys = (unsigned long long*)((char*)d_ws + L1_BLOCKS * sizeof(float));

    fused_kernel<<<TOPK_BLOCKS + L1_BLOCKS, TPB, 0, stream>>>(
        (const float4*)target, (const float4*)pred, nvec,
        latent, nLat, partials, keys);

    finalize_kernel<<<1, TPB, 0, stream>>>(
        partials, L1_BLOCKS, keys, R_xyz, G, out, 1.0f / (float)n);
}